// Round 7
// baseline (369.050 us; speedup 1.0000x reference)
//
#include <hip/hip_runtime.h>

#define Bc 2
#define Sc 2048
#define Hc 2048
#define NHc 16
#define HDc 128
#define SLOTSc 16
#define NROWS (Bc * Sc)   // 4096

typedef float v2f __attribute__((ext_vector_type(2)));  // native clang vector:
                                                        // works with __builtin_nontemporal_*

// ---------------------------------------------------------------------------
// Kernel 1: actions = softmax( (hidden @ W_action^T + b) / sqrt(128) )
// Block = 256 thr = 4 waves = 64 outputs (4 rows x 16 heads) x 4 K-chunks.
// Thread (o, kc): o = tid&63 -> (row_local = o>>4, head = o&15), kc = tid>>6.
// Each thread dots 512 elements; LDS combine over kc; thread o finishes
// softmax-3. Grid = 1024 blocks = 4096 waves (16/CU). W (384 KB) L2-resident.
// ---------------------------------------------------------------------------
__global__ __launch_bounds__(256) void actions_kernel(
    const float* __restrict__ hidden,    // [4096][2048]
    const float* __restrict__ W_action,  // [48][2048]
    const float* __restrict__ b_action,  // [48]
    float* __restrict__ actions)         // [4096][16][3]
{
    __shared__ float part[3][4][64];

    const int tid  = threadIdx.x;
    const int o    = tid & 63;
    const int kc   = tid >> 6;
    const int rl   = o >> 4;
    const int head = o & 15;
    const int r    = blockIdx.x * 4 + rl;
    const int c0   = 3 * head;

    const float4* A  = (const float4*)(hidden + (size_t)r * Hc + kc * 512);
    const float4* B0 = (const float4*)(W_action + (size_t)c0 * Hc + kc * 512);
    const float4* B1 = B0 + (Hc / 4);
    const float4* B2 = B1 + (Hc / 4);

    float s0 = 0.f, s1 = 0.f, s2 = 0.f;
    #pragma unroll 8
    for (int j = 0; j < 128; ++j) {
        float4 a  = A[j];
        float4 b0 = B0[j];
        float4 b1 = B1[j];
        float4 b2 = B2[j];
        s0 = fmaf(a.x, b0.x, fmaf(a.y, b0.y, fmaf(a.z, b0.z, fmaf(a.w, b0.w, s0))));
        s1 = fmaf(a.x, b1.x, fmaf(a.y, b1.y, fmaf(a.z, b1.z, fmaf(a.w, b1.w, s1))));
        s2 = fmaf(a.x, b2.x, fmaf(a.y, b2.y, fmaf(a.z, b2.z, fmaf(a.w, b2.w, s2))));
    }
    part[0][kc][o] = s0;
    part[1][kc][o] = s1;
    part[2][kc][o] = s2;
    __syncthreads();

    if (tid < 64) {
        float t0 = part[0][0][o] + part[0][1][o] + part[0][2][o] + part[0][3][o];
        float t1 = part[1][0][o] + part[1][1][o] + part[1][2][o] + part[1][3][o];
        float t2 = part[2][0][o] + part[2][1][o] + part[2][2][o] + part[2][3][o];
        const float scale = 0.08838834764831845f; // 1/sqrt(128)
        float l0 = (t0 + b_action[c0 + 0]) * scale;
        float l1 = (t1 + b_action[c0 + 1]) * scale;
        float l2 = (t2 + b_action[c0 + 2]) * scale;
        float lm = fmaxf(l0, fmaxf(l1, l2));
        float e0 = __expf(l0 - lm), e1 = __expf(l1 - lm), e2 = __expf(l2 - lm);
        float inv = 1.f / (e0 + e1 + e2);
        float* ap = actions + ((size_t)r * NHc + head) * 3;
        ap[0] = e0 * inv;
        ap[1] = e1 * inv;
        ap[2] = e2 * inv;
    }
}

// ---------------------------------------------------------------------------
// Kernel 2: pure streaming. One INDEPENDENT wave per (b,s,head): no LDS, no
// __syncthreads. Lane l owns dims 2l,2l+1 (v2f, 8B/lane coalesced).
// actions load issued FIRST (oldest in vmcnt queue -> its wait doesn't drain
// the sv burst). Stack load / new_stack store are nontemporal (zero reuse;
// keep L2/L3 for hidden/actions). Gate reduce = merge-butterfly
// reduce-scatter (17 shfl), distributed masked softmax (1 exp), 16 bpermute
// broadcast for the weighted sum. VGPR ~85 under the 128 cap: no spills.
// ---------------------------------------------------------------------------
__global__ __launch_bounds__(256, 4) void stack_stream(
    const float* __restrict__ hidden,     // [4096][2048]
    const float* __restrict__ stack,      // [4096][16][16][128]
    const float* __restrict__ mask,       // [4096][16][16]
    const float* __restrict__ actions,    // [4096][16][3]
    const float* __restrict__ W_gate,     // [128]
    const float* __restrict__ b_gate,     // [1]
    const float* __restrict__ res_weight, // [1]
    float* __restrict__ out,              // [4096][2048]
    float* __restrict__ new_stack,        // [4096][16][16][128]
    float* __restrict__ new_mask)         // [4096][16][16]
{
    const int bs   = blockIdx.x >> 2;
    const int hg   = blockIdx.x & 3;
    const int lane = threadIdx.x & 63;
    const int wave = threadIdx.x >> 6;
    const int n    = hg * 4 + wave;

    // ---- actions first (L2/L3-hit; oldest in queue) ----
    const float* ap = actions + ((size_t)bs * NHc + n) * 3;
    const float a_push = ap[0];
    const float a_pop  = ap[1];
    const float a_stay = ap[2];

    // ---- stack burst (nontemporal: streams past L2/L3) ----
    const size_t sbase = ((size_t)bs * NHc + n) * (size_t)(SLOTSc * HDc);
    const v2f* st2 = (const v2f*)(stack + sbase);
    v2f sv[SLOTSc];
    #pragma unroll
    for (int k = 0; k < SLOTSc; ++k)
        sv[k] = __builtin_nontemporal_load(&st2[k * 64 + lane]);

    v2f kv = *(const v2f*)(hidden + (size_t)bs * Hc + n * HDc + 2 * lane);
    v2f wg = *(const v2f*)(W_gate + 2 * lane);

    const int cls = lane & 15;
    const int grp = lane & 48;
    float m_d = mask[((size_t)bs * NHc + n) * SLOTSc + cls];

    // ---- distributed new_mask ----
    {
        int ap_prev = (grp | (cls == 0 ? 0 : cls - 1)) << 2;
        int ap_next = (grp | (cls == 15 ? 15 : cls + 1)) << 2;
        float m_prev = __int_as_float(__builtin_amdgcn_ds_bpermute(ap_prev, __float_as_int(m_d)));
        float m_next = __int_as_float(__builtin_amdgcn_ds_bpermute(ap_next, __float_as_int(m_d)));
        m_prev = (cls == 0)  ? 1.f : m_prev;
        m_next = (cls == 15) ? 0.f : m_next;
        m_d = a_push * m_prev + a_pop * m_next + a_stay * m_d;  // now new_mask
    }
    if (lane < SLOTSc)
        new_mask[((size_t)bs * NHc + n) * SLOTSc + lane] = m_d;

    // ---- new_stack (in-place on sv) + nt stores + gate partials ----
    const float bg = b_gate[0];
    const float rw = res_weight[0];
    v2f* nst2 = (v2f*)(new_stack + sbase);
    float p[SLOTSc];
    {
        v2f prev = kv;
        #pragma unroll
        for (int k = 0; k < SLOTSc; ++k) {
            v2f cur = sv[k];
            v2f nxt;
            if (k < SLOTSc - 1) nxt = sv[k + 1];
            else { nxt.x = 0.f; nxt.y = 0.f; }
            v2f ns;
            ns.x = a_push * prev.x + a_pop * nxt.x + a_stay * cur.x;
            ns.y = a_push * prev.y + a_pop * nxt.y + a_stay * cur.y;
            sv[k] = ns;
            __builtin_nontemporal_store(ns, &nst2[k * 64 + lane]);
            p[k] = ns.x * wg.x + ns.y * wg.y;
            prev = cur;
        }
    }

    // ---- merge-butterfly reduce-scatter (slot k -> lanes l&15==k) ----
    float w8[8];
    #pragma unroll
    for (int j = 0; j < 8; ++j) {
        float a = p[2 * j], b = p[2 * j + 1];
        bool hi = (lane & 1);
        float keep = hi ? b : a;
        float send = hi ? a : b;
        w8[j] = keep + __shfl_xor(send, 1, 64);
    }
    float w4[4];
    #pragma unroll
    for (int j = 0; j < 4; ++j) {
        float a = w8[2 * j], b = w8[2 * j + 1];
        bool hi = (lane & 2);
        float keep = hi ? b : a;
        float send = hi ? a : b;
        w4[j] = keep + __shfl_xor(send, 2, 64);
    }
    float w2[2];
    #pragma unroll
    for (int j = 0; j < 2; ++j) {
        float a = w4[2 * j], b = w4[2 * j + 1];
        bool hi = (lane & 4);
        float keep = hi ? b : a;
        float send = hi ? a : b;
        w2[j] = keep + __shfl_xor(send, 4, 64);
    }
    float u;
    {
        float a = w2[0], b = w2[1];
        bool hi = (lane & 8);
        float keep = hi ? b : a;
        float send = hi ? a : b;
        u = keep + __shfl_xor(send, 8, 64);
    }
    u += __shfl_xor(u, 16, 64);
    u += __shfl_xor(u, 32, 64);
    // u = dot(new_stack[l&15], W_gate) over all 128 dims

    // ---- distributed masked softmax over 16 slots ----
    float g = u + bg + (1.f - m_d) * -1000000000.0f;
    float mx = g;
    mx = fmaxf(mx, __shfl_xor(mx, 1, 64));
    mx = fmaxf(mx, __shfl_xor(mx, 2, 64));
    mx = fmaxf(mx, __shfl_xor(mx, 4, 64));
    mx = fmaxf(mx, __shfl_xor(mx, 8, 64));
    float e = __expf(g - mx);
    float ssum = e;
    ssum += __shfl_xor(ssum, 1, 64);
    ssum += __shfl_xor(ssum, 2, 64);
    ssum += __shfl_xor(ssum, 4, 64);
    ssum += __shfl_xor(ssum, 8, 64);
    float gw_d = e / ssum;   // gate weight for slot l&15

    // ---- broadcast gate weights; weighted sum + residual ----
    v2f mo; mo.x = 0.f; mo.y = 0.f;
    const int grpb = grp << 2;
    #pragma unroll
    for (int k = 0; k < SLOTSc; ++k) {
        float gwk = __int_as_float(
            __builtin_amdgcn_ds_bpermute(grpb | (k << 2), __float_as_int(gw_d)));
        mo.x = fmaf(gwk, sv[k].x, mo.x);
        mo.y = fmaf(gwk, sv[k].y, mo.y);
    }
    v2f ov;
    ov.x = mo.x * rw + kv.x;
    ov.y = mo.y * rw + kv.y;
    __builtin_nontemporal_store(ov, (v2f*)(out + (size_t)bs * Hc + n * HDc + 2 * lane));
}

extern "C" void kernel_launch(void* const* d_in, const int* in_sizes, int n_in,
                              void* d_out, int out_size, void* d_ws, size_t ws_size,
                              hipStream_t stream) {
    const float* hidden     = (const float*)d_in[0];
    const float* stack      = (const float*)d_in[1];
    const float* mask       = (const float*)d_in[2];
    const float* W_action   = (const float*)d_in[3];
    const float* b_action   = (const float*)d_in[4];
    const float* W_gate     = (const float*)d_in[5];
    const float* b_gate     = (const float*)d_in[6];
    const float* res_weight = (const float*)d_in[7];

    float* out       = (float*)d_out;
    float* new_stack = out + (size_t)Bc * Sc * Hc;
    float* new_mask  = new_stack + (size_t)Bc * Sc * NHc * SLOTSc * HDc;

    float* actions = (float*)d_ws; // 4096*16*3*4 = 786,432 B

    hipLaunchKernelGGL(actions_kernel, dim3(NROWS / 4), dim3(256), 0, stream,
                       hidden, W_action, b_action, actions);

    hipLaunchKernelGGL(stack_stream, dim3(NROWS * 4), dim3(256), 0, stream,
                       hidden, stack, mask, actions, W_gate, b_gate, res_weight,
                       out, new_stack, new_mask);
}

// Round 8
// 239.318 us; speedup vs baseline: 1.5421x; 1.5421x over previous
//
#include <hip/hip_runtime.h>

#define Bc 2
#define Sc 2048
#define Hc 2048
#define NHc 16
#define HDc 128
#define SLOTSc 16
#define NROWS (Bc * Sc)   // 4096

typedef float v2f __attribute__((ext_vector_type(2)));

// ---------------------------------------------------------------------------
// Fused kernel (R5 structure + load-order fix).
// Block = 512 thr = 8 waves = 8 heads of one (b,s) row; grid = NROWS*2.
// Lane l owns dims 2l,2l+1 of its head (8B/lane coalesced).
//
// Load-order discipline (vmcnt retires IN ORDER, so slow loads must not sit
// ahead of fast ones in the queue):
//   pre-barrier : hidden staging float4 only (fast, 8 KB/block)
//   phase 1     : GEMV W loads (L2-resident) + LDS reads -> logits
//   then        : sched_barrier(0); issue 16-slot sv HBM burst; its latency
//                 hides under the 18-shfl reduce + softmax-3 + new_mask phase
//   phase 3     : consume sv (new_stack compute/store + gate partials)
//   phase 4     : reduce-scatter, distributed masked softmax (1 exp),
//                 bpermute broadcast, weighted sum, residual, store.
// ---------------------------------------------------------------------------
__global__ __launch_bounds__(512, 4) void stack_fused(
    const float* __restrict__ hidden,     // [4096][2048]
    const float* __restrict__ stack,      // [4096][16][16][128]
    const float* __restrict__ mask,       // [4096][16][16]
    const float* __restrict__ W_action,   // [48][2048]
    const float* __restrict__ b_action,   // [48]
    const float* __restrict__ W_gate,     // [128]
    const float* __restrict__ b_gate,     // [1]
    const float* __restrict__ res_weight, // [1]
    float* __restrict__ out,              // [4096][2048]
    float* __restrict__ new_stack,        // [4096][16][16][128]
    float* __restrict__ new_mask)         // [4096][16][16]
{
    __shared__ float hid[Hc]; // 8 KB

    const int bs   = blockIdx.x >> 1;
    const int half = blockIdx.x & 1;
    const int tid  = threadIdx.x;
    const int lane = tid & 63;
    const int wave = tid >> 6;
    const int n    = half * 8 + wave;

    // ---- phase 0: hidden staging ONLY (keep the vmcnt queue clean) ----
    const float4* hrow4 = (const float4*)(hidden + (size_t)bs * Hc);
    ((float4*)hid)[tid] = hrow4[tid]; // 512 thr x 16B = 8 KB
    __syncthreads();

    // ---- phase 1: GEMV (W L2-resident; no slow loads ahead in queue) ----
    float s0 = 0.f, s1 = 0.f, s2 = 0.f;
    {
        const float4* hl = (const float4*)hid;
        const float4* W0 = (const float4*)(W_action + (size_t)(3 * n) * Hc);
        const float4* W1 = W0 + (Hc / 4);
        const float4* W2 = W1 + (Hc / 4);
        #pragma unroll 2
        for (int j = 0; j < 8; ++j) {
            float4 a  = hl[lane + j * 64];
            float4 b0 = W0[lane + j * 64];
            float4 b1 = W1[lane + j * 64];
            float4 b2 = W2[lane + j * 64];
            s0 = fmaf(a.x, b0.x, fmaf(a.y, b0.y, fmaf(a.z, b0.z, fmaf(a.w, b0.w, s0))));
            s1 = fmaf(a.x, b1.x, fmaf(a.y, b1.y, fmaf(a.z, b1.z, fmaf(a.w, b1.w, s1))));
            s2 = fmaf(a.x, b2.x, fmaf(a.y, b2.y, fmaf(a.z, b2.z, fmaf(a.w, b2.w, s2))));
        }
    }

    // ---- issue the sv HBM burst NOW (after last W load, before the long
    //      shuffle/softmax stretch). sched_barrier pins the issue point. ----
    __builtin_amdgcn_sched_barrier(0);
    const size_t sbase = ((size_t)bs * NHc + n) * (size_t)(SLOTSc * HDc);
    const v2f* st2 = (const v2f*)(stack + sbase);
    v2f sv[SLOTSc];
    #pragma unroll
    for (int k = 0; k < SLOTSc; ++k) sv[k] = st2[k * 64 + lane];

    const int cls = lane & 15;
    const int grp = lane & 48;
    float m_d = mask[((size_t)bs * NHc + n) * SLOTSc + cls];
    v2f wg = *(const v2f*)(W_gate + 2 * lane);
    v2f kv = *(const v2f*)(hid + n * HDc + 2 * lane);
    __builtin_amdgcn_sched_barrier(0);

    // ---- finish logits: 18-shfl reduce + softmax-3 (hides sv latency) ----
    #pragma unroll
    for (int o = 32; o; o >>= 1) {
        s0 += __shfl_xor(s0, o, 64);
        s1 += __shfl_xor(s1, o, 64);
        s2 += __shfl_xor(s2, o, 64);
    }
    const float scale = 0.08838834764831845f; // 1/sqrt(128)
    float l0 = (s0 + b_action[3 * n + 0]) * scale;
    float l1 = (s1 + b_action[3 * n + 1]) * scale;
    float l2 = (s2 + b_action[3 * n + 2]) * scale;
    float lm = fmaxf(l0, fmaxf(l1, l2));
    float e0 = __expf(l0 - lm), e1 = __expf(l1 - lm), e2 = __expf(l2 - lm);
    float inv3 = 1.f / (e0 + e1 + e2);
    const float a_push = e0 * inv3;
    const float a_pop  = e1 * inv3;
    const float a_stay = e2 * inv3;

    // ---- distributed new_mask (2 bpermute) ----
    {
        int ap_prev = (grp | (cls == 0 ? 0 : cls - 1)) << 2;
        int ap_next = (grp | (cls == 15 ? 15 : cls + 1)) << 2;
        float m_prev = __int_as_float(__builtin_amdgcn_ds_bpermute(ap_prev, __float_as_int(m_d)));
        float m_next = __int_as_float(__builtin_amdgcn_ds_bpermute(ap_next, __float_as_int(m_d)));
        m_prev = (cls == 0)  ? 1.f : m_prev;
        m_next = (cls == 15) ? 0.f : m_next;
        m_d = a_push * m_prev + a_pop * m_next + a_stay * m_d;  // now new_mask
    }
    if (lane < SLOTSc)
        new_mask[((size_t)bs * NHc + n) * SLOTSc + lane] = m_d;

    // ---- phase 3: new_stack (in-place on sv) + stores + gate partials ----
    const float bg = b_gate[0];
    const float rw = res_weight[0];
    v2f* nst2 = (v2f*)(new_stack + sbase);
    float p[SLOTSc];
    {
        v2f prev = kv;
        #pragma unroll
        for (int k = 0; k < SLOTSc; ++k) {
            v2f cur = sv[k];
            v2f nxt;
            if (k < SLOTSc - 1) nxt = sv[k + 1];
            else { nxt.x = 0.f; nxt.y = 0.f; }
            v2f ns;
            ns.x = a_push * prev.x + a_pop * nxt.x + a_stay * cur.x;
            ns.y = a_push * prev.y + a_pop * nxt.y + a_stay * cur.y;
            sv[k] = ns;
            nst2[k * 64 + lane] = ns;
            p[k] = ns.x * wg.x + ns.y * wg.y;
            prev = cur;
        }
    }

    // ---- phase 4a: merge-butterfly reduce-scatter (slot k -> lane&15==k) ----
    float w8[8];
    #pragma unroll
    for (int j = 0; j < 8; ++j) {
        float a = p[2 * j], b = p[2 * j + 1];
        bool hi = (lane & 1);
        float keep = hi ? b : a;
        float send = hi ? a : b;
        w8[j] = keep + __shfl_xor(send, 1, 64);
    }
    float w4[4];
    #pragma unroll
    for (int j = 0; j < 4; ++j) {
        float a = w8[2 * j], b = w8[2 * j + 1];
        bool hi = (lane & 2);
        float keep = hi ? b : a;
        float send = hi ? a : b;
        w4[j] = keep + __shfl_xor(send, 2, 64);
    }
    float w2[2];
    #pragma unroll
    for (int j = 0; j < 2; ++j) {
        float a = w4[2 * j], b = w4[2 * j + 1];
        bool hi = (lane & 4);
        float keep = hi ? b : a;
        float send = hi ? a : b;
        w2[j] = keep + __shfl_xor(send, 4, 64);
    }
    float u;
    {
        float a = w2[0], b = w2[1];
        bool hi = (lane & 8);
        float keep = hi ? b : a;
        float send = hi ? a : b;
        u = keep + __shfl_xor(send, 8, 64);
    }
    u += __shfl_xor(u, 16, 64);
    u += __shfl_xor(u, 32, 64);
    // u = dot(new_stack[l&15], W_gate) over all 128 dims

    // ---- phase 4b: distributed masked softmax over 16 slots ----
    float g = u + bg + (1.f - m_d) * -1000000000.0f;
    float mx = g;
    mx = fmaxf(mx, __shfl_xor(mx, 1, 64));
    mx = fmaxf(mx, __shfl_xor(mx, 2, 64));
    mx = fmaxf(mx, __shfl_xor(mx, 4, 64));
    mx = fmaxf(mx, __shfl_xor(mx, 8, 64));
    float e = __expf(g - mx);
    float ssum = e;
    ssum += __shfl_xor(ssum, 1, 64);
    ssum += __shfl_xor(ssum, 2, 64);
    ssum += __shfl_xor(ssum, 4, 64);
    ssum += __shfl_xor(ssum, 8, 64);
    float gw_d = e / ssum;   // gate weight for slot l&15

    // ---- phase 4c: broadcast gate weights; weighted sum + residual ----
    v2f mo; mo.x = 0.f; mo.y = 0.f;
    const int grpb = grp << 2;
    #pragma unroll
    for (int k = 0; k < SLOTSc; ++k) {
        float gwk = __int_as_float(
            __builtin_amdgcn_ds_bpermute(grpb | (k << 2), __float_as_int(gw_d)));
        mo.x = fmaf(gwk, sv[k].x, mo.x);
        mo.y = fmaf(gwk, sv[k].y, mo.y);
    }
    v2f ov;
    ov.x = mo.x * rw + kv.x;
    ov.y = mo.y * rw + kv.y;
    *(v2f*)(out + (size_t)bs * Hc + n * HDc + 2 * lane) = ov;
}

extern "C" void kernel_launch(void* const* d_in, const int* in_sizes, int n_in,
                              void* d_out, int out_size, void* d_ws, size_t ws_size,
                              hipStream_t stream) {
    const float* hidden     = (const float*)d_in[0];
    const float* stack      = (const float*)d_in[1];
    const float* mask       = (const float*)d_in[2];
    const float* W_action   = (const float*)d_in[3];
    const float* b_action   = (const float*)d_in[4];
    const float* W_gate     = (const float*)d_in[5];
    const float* b_gate     = (const float*)d_in[6];
    const float* res_weight = (const float*)d_in[7];

    float* out       = (float*)d_out;
    float* new_stack = out + (size_t)Bc * Sc * Hc;
    float* new_mask  = new_stack + (size_t)Bc * Sc * NHc * SLOTSc * HDc;

    hipLaunchKernelGGL(stack_fused, dim3(NROWS * 2), dim3(512), 0, stream,
                       hidden, stack, mask, W_action, b_action,
                       W_gate, b_gate, res_weight,
                       out, new_stack, new_mask);
}